// Round 7
// baseline (362.684 us; speedup 1.0000x reference)
//
#include <hip/hip_runtime.h>
#include <math.h>

#define B_ 8
#define C_ 256
#define C2_ 512
#define DK_ 32
#define HW_ 2304

// ws layout (floats):
#define WS_WQ   0        // wq_eff [8][256]
#define WS_VG   2048     // vg     [8][256]
#define WS_QB   4096     // qb     [8]
#define WS_FLAG 4160     // 72 flag words: [b*9+0]=wq/qb ready, [b*9+1+t]=vg tile t
#define MAGIC   0x5A7E1239u

#define NPREP 64         // blocks 0..63 prep, 64..639 fused tiles

__device__ __forceinline__ float gelu_exact(float x) {
    return 0.5f * x * (1.0f + erff(x * 0.70710678118654752f));
}

__global__ __launch_bounds__(256) void k_one(
    const float* __restrict__ img,  const float* __restrict__ text,
    const float* __restrict__ l,
    const float* __restrict__ Wg1,  const float* __restrict__ bg1,
    const float* __restrict__ ln_g, const float* __restrict__ ln_b,
    const float* __restrict__ Wg2,  const float* __restrict__ bg2,
    const float* __restrict__ Wq,   const float* __restrict__ bq,
    const float* __restrict__ Wk,   const float* __restrict__ Wv,
    const float* __restrict__ bv,   const float* __restrict__ gamma,
    float* __restrict__ ws,         float* __restrict__ out)
{
    const int blk = blockIdx.x;
    const int tid = threadIdx.x;
    unsigned int* wsu = (unsigned int*)ws;

    __shared__ __align__(16) float lsh[HW_];   // prep scratch / l broadcast
    __shared__ float tile[C_][32];
    __shared__ float wq[C_], vgb[C_], bvs[C_];
    __shared__ float part[8][32];
    __shared__ float aa[32], ss[32];
    __shared__ float redmn[4], redmx[4];

    if (blk < NPREP) {
        // ---------------- prep path (pb, tile8) — verified in R6 ----------------
        const int pb = blk >> 3;
        const int tile8 = blk & 7;
        float* tx  = lsh;            // 256
        float* tsh = lsh + 256;      // 512
        float* gvs = lsh + 768;      // 256
        float* r1  = lsh + 1536;     // 4
        float* r2  = lsh + 1544;     // 4
        float* kg  = lsh + 1552;     // 32

        tx[tid] = text[pb * C_ + tid];
        __syncthreads();

        float a0 = bg1[tid], a1 = bg1[tid + 256];
        #pragma unroll 8
        for (int c = 0; c < C_; ++c) {
            float t = tx[c];
            a0 += t * Wg1[(size_t)c * C2_ + tid];
            a1 += t * Wg1[(size_t)c * C2_ + tid + 256];
        }
        float s1 = a0 + a1, s2 = a0 * a0 + a1 * a1;
        for (int o = 32; o; o >>= 1) {
            s1 += __shfl_down(s1, o);
            s2 += __shfl_down(s2, o);
        }
        if ((tid & 63) == 0) { r1[tid >> 6] = s1; r2[tid >> 6] = s2; }
        __syncthreads();
        s1 = r1[0] + r1[1] + r1[2] + r1[3];
        s2 = r2[0] + r2[1] + r2[2] + r2[3];
        const float mu = s1 * (1.0f / 512.0f);
        const float rstd = rsqrtf(s2 * (1.0f / 512.0f) - mu * mu + 1e-5f);
        float g0 = gelu_exact((a0 - mu) * rstd * ln_g[tid] + ln_b[tid]);
        float g1 = gelu_exact((a1 - mu) * rstd * ln_g[tid + 256] + ln_b[tid + 256]);
        __syncthreads();
        tsh[tid] = g0; tsh[tid + 256] = g1;
        __syncthreads();

        float g = bg2[tid];
        #pragma unroll 8
        for (int j = 0; j < C2_; ++j)
            g += tsh[j] * Wg2[(size_t)j * C_ + tid];
        gvs[tid] = g;
        __syncthreads();

        const int o = tid >> 3, su = tid & 7;
        const float4* gv4 = (const float4*)gvs + su * 8;
        {
            const float4* wrow = (const float4*)(Wv + (size_t)(tile8 * 32 + o) * C_) + su * 8;
            float a = 0.f;
            #pragma unroll
            for (int k4 = 0; k4 < 8; ++k4) {
                float4 w4 = wrow[k4], q4 = gv4[k4];
                a += w4.x * q4.x + w4.y * q4.y + w4.z * q4.z + w4.w * q4.w;
            }
            a += __shfl_xor(a, 1);
            a += __shfl_xor(a, 2);
            a += __shfl_xor(a, 4);
            if (su == 0) ws[WS_VG + pb * C_ + tile8 * 32 + o] = a;
        }
        if (tile8 == 0) {
            const float4* wrow = (const float4*)(Wk + (size_t)o * C_) + su * 8;
            float a = 0.f;
            #pragma unroll
            for (int k4 = 0; k4 < 8; ++k4) {
                float4 w4 = wrow[k4], q4 = gv4[k4];
                a += w4.x * q4.x + w4.y * q4.y + w4.z * q4.z + w4.w * q4.w;
            }
            a += __shfl_xor(a, 1);
            a += __shfl_xor(a, 2);
            a += __shfl_xor(a, 4);
            if (su == 0) kg[o] = a;
            __syncthreads();
            float w = 0.f;
            #pragma unroll
            for (int d = 0; d < DK_; ++d) w += kg[d] * Wq[(size_t)d * C_ + tid];
            ws[WS_WQ + pb * C_ + tid] = w;
            if (tid == 0) {
                float q = 0.f;
                #pragma unroll
                for (int d = 0; d < DK_; ++d) q += kg[d] * bq[d];
                ws[WS_QB + pb] = q;
            }
        }
        // publish: data -> fence -> barrier -> release flag
        __threadfence();
        __syncthreads();
        if (tid == 0) {
            __hip_atomic_store(&wsu[WS_FLAG + pb * 9 + 1 + tile8], MAGIC,
                               __ATOMIC_RELEASE, __HIP_MEMORY_SCOPE_AGENT);
            if (tile8 == 0)
                __hip_atomic_store(&wsu[WS_FLAG + pb * 9 + 0], MAGIC,
                                   __ATOMIC_RELEASE, __HIP_MEMORY_SCOPE_AGENT);
        }
        return;
    }

    // ---------------- fused path: prep-independent work first ----------------
    const int idx = blk - NPREP;         // 576 = 8 b * 72 tiles
    const int b = idx / 72;
    const int i0 = (idx % 72) * 32;
    const int pix = tid & 31, sub = tid >> 5;

    bvs[tid] = bv[tid];
    float mn = 1e30f, mx = -1e30f;
    #pragma unroll
    for (int j = tid; j < HW_; j += 256) {
        float v = l[j];
        lsh[j] = v;
        mn = fminf(mn, v); mx = fmaxf(mx, v);
    }
    for (int o = 32; o; o >>= 1) {
        mn = fminf(mn, __shfl_down(mn, o));
        mx = fmaxf(mx, __shfl_down(mx, o));
    }
    if ((tid & 63) == 0) { redmn[tid >> 6] = mn; redmx[tid >> 6] = mx; }

    {
        const float* x = img + ((size_t)b * C_ + sub * 32) * HW_ + i0 + pix;
        #pragma unroll 8
        for (int k = 0; k < 32; ++k)
            tile[sub * 32 + k][pix] = x[(size_t)k * HW_];
    }
    __syncthreads();
    const float lmin = fminf(fminf(redmn[0], redmn[1]), fminf(redmn[2], redmn[3]));
    const float lmax = fmaxf(fmaxf(redmx[0], redmx[1]), fmaxf(redmx[2], redmx[3]));

    // wait for this batch's producer flags (no-op on timed replays)
    if (tid < 9) {
        while (__hip_atomic_load(&wsu[WS_FLAG + b * 9 + tid],
                                 __ATOMIC_ACQUIRE, __HIP_MEMORY_SCOPE_AGENT) != MAGIC)
            __builtin_amdgcn_s_sleep(8);
    }
    __syncthreads();

    wq[tid]  = __hip_atomic_load(&ws[WS_WQ + b * C_ + tid],
                                 __ATOMIC_RELAXED, __HIP_MEMORY_SCOPE_AGENT);
    vgb[tid] = __hip_atomic_load(&ws[WS_VG + b * C_ + tid],
                                 __ATOMIC_RELAXED, __HIP_MEMORY_SCOPE_AGENT);
    __syncthreads();

    // a[pix] partial dots from LDS tile
    {
        float acc = 0.f;
        #pragma unroll 8
        for (int k = 0; k < 32; ++k)
            acc += wq[sub * 32 + k] * tile[sub * 32 + k][pix];
        part[sub][pix] = acc;
    }
    __syncthreads();
    if (tid < 32) {
        float a = __hip_atomic_load(&ws[WS_QB + b],
                                    __ATOMIC_RELAXED, __HIP_MEMORY_SCOPE_AGENT);
        #pragma unroll
        for (int u = 0; u < 8; ++u) a += part[u][tid];
        aa[tid] = a;
    }
    __syncthreads();

    // s[pix] = sum_j l[j] e(j) / sum_j e(j),  e = exp(a*l[j]-mx)
    {
        const int spix = tid >> 3, ssub = tid & 7;
        const float m = aa[spix];
        const float mxv = (m >= 0.f) ? m * lmax : m * lmin;
        float se = 0.f, sle = 0.f;
        #pragma unroll 4
        for (int j = ssub; j < HW_; j += 8) {
            float lj = lsh[j];
            float e = __expf(m * lj - mxv);
            se += e;
            sle += e * lj;
        }
        se += __shfl_xor(se, 1);  sle += __shfl_xor(sle, 1);
        se += __shfl_xor(se, 2);  sle += __shfl_xor(sle, 2);
        se += __shfl_xor(se, 4);  sle += __shfl_xor(sle, 4);
        if (ssub == 0) ss[spix] = sle / se;
    }
    __syncthreads();

    // out = tile + g*(vg*s + bv)
    {
        const float g = gamma[0];
        const float s = ss[pix];
        float* o = out + ((size_t)b * C_ + sub * 32) * HW_ + i0 + pix;
        #pragma unroll 8
        for (int k = 0; k < 32; ++k) {
            const int c = sub * 32 + k;
            o[(size_t)k * HW_] = tile[c][pix] + g * (vgb[c] * s + bvs[c]);
        }
    }
}

extern "C" void kernel_launch(void* const* d_in, const int* in_sizes, int n_in,
                              void* d_out, int out_size, void* d_ws, size_t ws_size,
                              hipStream_t stream) {
    const float* img   = (const float*)d_in[0];
    const float* text  = (const float*)d_in[1];
    const float* l     = (const float*)d_in[2];
    const float* Wg1   = (const float*)d_in[3];
    const float* bg1   = (const float*)d_in[4];
    const float* ln_g  = (const float*)d_in[5];
    const float* ln_b  = (const float*)d_in[6];
    const float* Wg2   = (const float*)d_in[7];
    const float* bg2   = (const float*)d_in[8];
    const float* Wq    = (const float*)d_in[9];
    const float* bq    = (const float*)d_in[10];
    const float* Wk    = (const float*)d_in[11];
    // bk (d_in[12]) cancels in the softmax — unused
    const float* Wv    = (const float*)d_in[13];
    const float* bv    = (const float*)d_in[14];
    const float* gamma = (const float*)d_in[15];
    float* out = (float*)d_out;
    float* ws  = (float*)d_ws;

    k_one<<<NPREP + 576, 256, 0, stream>>>(img, text, l, Wg1, bg1, ln_g, ln_b,
                                           Wg2, bg2, Wq, bq, Wk, Wv, bv, gamma,
                                           ws, out);
}

// Round 8
// 47.358 us; speedup vs baseline: 7.6583x; 7.6583x over previous
//
#include <hip/hip_runtime.h>
#include <math.h>

#define B_ 8
#define C_ 256
#define C2_ 512
#define DK_ 32
#define HW_ 2304

// ws layout (floats):
#define WS_WQ   0        // wq_eff [8][256]
#define WS_VG   2048     // vg     [8][256]
#define WS_QB   4096     // qb     [8]

__device__ __forceinline__ float gelu_exact(float x) {
    return 0.5f * x * (1.0f + erff(x * 0.70710678118654752f));
}

// One block = (b, tile). Redundantly computes the whole text path for batch b
// (tiny, L2-served), then writes its 32-row tile of vg. tile==0 also computes
// kg -> wq_eff, qb.  [verified R3 code, unchanged]
__global__ __launch_bounds__(512) void k_prep(
    const float* __restrict__ text,
    const float* __restrict__ Wg1,  const float* __restrict__ bg1,
    const float* __restrict__ ln_g, const float* __restrict__ ln_b,
    const float* __restrict__ Wg2,  const float* __restrict__ bg2,
    const float* __restrict__ Wq,   const float* __restrict__ bq,
    const float* __restrict__ Wk,   const float* __restrict__ Wv,
    float* __restrict__ ws)
{
    const int b = blockIdx.x >> 3;
    const int tile = blockIdx.x & 7;
    const int tid = threadIdx.x;

    __shared__ float tx[C_];
    __shared__ __align__(16) float tsh[C2_];
    __shared__ __align__(16) float gvs[C_];
    __shared__ float part2[2][C_];
    __shared__ float r1[8], r2[8];
    __shared__ float kg[DK_];

    if (tid < C_) tx[tid] = text[b * C_ + tid];
    __syncthreads();

    float acc = bg1[tid];
    #pragma unroll 8
    for (int c = 0; c < C_; ++c)
        acc += tx[c] * Wg1[(size_t)c * C2_ + tid];

    float s1 = acc, s2 = acc * acc;
    for (int o = 32; o; o >>= 1) {
        s1 += __shfl_down(s1, o);
        s2 += __shfl_down(s2, o);
    }
    if ((tid & 63) == 0) { r1[tid >> 6] = s1; r2[tid >> 6] = s2; }
    __syncthreads();
    s1 = 0.f; s2 = 0.f;
    #pragma unroll
    for (int u = 0; u < 8; ++u) { s1 += r1[u]; s2 += r2[u]; }
    const float mu = s1 * (1.0f / 512.0f);
    const float rstd = rsqrtf(s2 * (1.0f / 512.0f) - mu * mu + 1e-5f);
    tsh[tid] = gelu_exact((acc - mu) * rstd * ln_g[tid] + ln_b[tid]);
    __syncthreads();

    {
        const int col = tid & 255, half = tid >> 8;
        float g = 0.f;
        const float* wcol = Wg2 + (size_t)(half * 256) * C_ + col;
        #pragma unroll 8
        for (int j = 0; j < 256; ++j)
            g += tsh[half * 256 + j] * wcol[(size_t)j * C_];
        part2[half][col] = g;
    }
    __syncthreads();
    if (tid < C_) gvs[tid] = part2[0][tid] + part2[1][tid] + bg2[tid];
    __syncthreads();

    const int o = tid >> 4, sub = tid & 15;
    const float4* gv4 = (const float4*)gvs + sub * 4;
    {
        const float4* wrow = (const float4*)(Wv + (size_t)(tile * 32 + o) * C_) + sub * 4;
        float a = 0.f;
        #pragma unroll
        for (int k4 = 0; k4 < 4; ++k4) {
            float4 w4 = wrow[k4], g4 = gv4[k4];
            a += w4.x * g4.x + w4.y * g4.y + w4.z * g4.z + w4.w * g4.w;
        }
        a += __shfl_xor(a, 1);
        a += __shfl_xor(a, 2);
        a += __shfl_xor(a, 4);
        a += __shfl_xor(a, 8);
        if (sub == 0) ws[WS_VG + b * C_ + tile * 32 + o] = a;
    }

    if (tile == 0) {
        const float4* wrow = (const float4*)(Wk + (size_t)o * C_) + sub * 4;
        float a = 0.f;
        #pragma unroll
        for (int k4 = 0; k4 < 4; ++k4) {
            float4 w4 = wrow[k4], g4 = gv4[k4];
            a += w4.x * g4.x + w4.y * g4.y + w4.z * g4.z + w4.w * g4.w;
        }
        a += __shfl_xor(a, 1);
        a += __shfl_xor(a, 2);
        a += __shfl_xor(a, 4);
        a += __shfl_xor(a, 8);
        if (sub == 0) kg[o] = a;
        __syncthreads();
        if (tid < C_) {
            float w = 0.f;
            #pragma unroll
            for (int d = 0; d < DK_; ++d) w += kg[d] * Wq[(size_t)d * C_ + tid];
            ws[WS_WQ + b * C_ + tid] = w;
        }
        if (tid == 0) {
            float q = 0.f;
            #pragma unroll
            for (int d = 0; d < DK_; ++d) q += kg[d] * bq[d];
            ws[WS_QB + b] = q;
        }
    }
}

// One block = (b, 32-pixel tile). img tile cached in REGISTERS (8x float4),
// float4 global loads/stores; a -> softmax-s -> out, no LDS img round-trip.
__global__ __launch_bounds__(256) void k_fused(
    const float* __restrict__ img, const float* __restrict__ l,
    const float* __restrict__ bv,  const float* __restrict__ gamma,
    const float* __restrict__ ws,  float* __restrict__ out)
{
    const int blk = blockIdx.x;          // 576 = 8 b * 72 tiles
    const int b = blk / 72;
    const int i0 = (blk % 72) * 32;
    const int tid = threadIdx.x;

    __shared__ __align__(16) float lsh[HW_];
    __shared__ float wq[C_], Asc[C_], Bsc[C_];
    __shared__ float part[32][36];       // [cl][pix], pad 36 to break banks
    __shared__ float aa[32], ss[32];
    __shared__ float redmn[4], redmx[4];

    const float g = gamma[0];
    wq[tid]  = ws[WS_WQ + b * C_ + tid];
    Asc[tid] = g * ws[WS_VG + b * C_ + tid];
    Bsc[tid] = g * bv[tid];

    // l -> LDS via float4, fused min/max
    float mn = 1e30f, mx = -1e30f;
    {
        const float4* l4 = (const float4*)l;
        for (int j = tid; j < HW_ / 4; j += 256) {
            float4 v = l4[j];
            ((float4*)lsh)[j] = v;
            mn = fminf(mn, fminf(fminf(v.x, v.y), fminf(v.z, v.w)));
            mx = fmaxf(mx, fmaxf(fmaxf(v.x, v.y), fmaxf(v.z, v.w)));
        }
    }
    for (int o = 32; o; o >>= 1) {
        mn = fminf(mn, __shfl_down(mn, o));
        mx = fmaxf(mx, __shfl_down(mx, o));
    }
    if ((tid & 63) == 0) { redmn[tid >> 6] = mn; redmx[tid >> 6] = mx; }

    // img tile -> registers (8 channels x 4 pixels per thread)
    const int p4 = tid & 7, cl = tid >> 3;   // p4: float4-pixel slot, cl: channel lane
    const float4* img4 = (const float4*)(img + (size_t)b * C_ * HW_ + i0);
    float4 cache[8];
    #pragma unroll
    for (int k = 0; k < 8; ++k)
        cache[k] = img4[(size_t)(k * 32 + cl) * (HW_ / 4) + p4];

    __syncthreads();   // wq/lsh/redmn ready

    // a-partials: 4 pixel-partials over this thread's 8 channels
    {
        float4 pa = make_float4(0.f, 0.f, 0.f, 0.f);
        #pragma unroll
        for (int k = 0; k < 8; ++k) {
            const float w = wq[k * 32 + cl];
            pa.x = fmaf(w, cache[k].x, pa.x);
            pa.y = fmaf(w, cache[k].y, pa.y);
            pa.z = fmaf(w, cache[k].z, pa.z);
            pa.w = fmaf(w, cache[k].w, pa.w);
        }
        part[cl][p4 * 4 + 0] = pa.x;
        part[cl][p4 * 4 + 1] = pa.y;
        part[cl][p4 * 4 + 2] = pa.z;
        part[cl][p4 * 4 + 3] = pa.w;
    }
    const float lmin = fminf(fminf(redmn[0], redmn[1]), fminf(redmn[2], redmn[3]));
    const float lmax = fmaxf(fmaxf(redmx[0], redmx[1]), fmaxf(redmx[2], redmx[3]));
    __syncthreads();   // part ready

    if (tid < 32) {
        float a = ws[WS_QB + b];
        #pragma unroll 8
        for (int u = 0; u < 32; ++u) a += part[u][tid];
        aa[tid] = a;
    }
    __syncthreads();   // aa ready

    // s[pix] = sum_j l[j]*e(j) / sum_j e(j),  e = exp(a*l[j]-mx); 32 pix x 8 lanes
    {
        const int spix = tid >> 3, ssub = tid & 7;
        const float m = aa[spix];
        const float mxv = (m >= 0.f) ? m * lmax : m * lmin;
        float se = 0.f, sle = 0.f;
        #pragma unroll 4
        for (int j = ssub; j < HW_; j += 8) {
            float lj = lsh[j];
            float e = __expf(fmaf(m, lj, -mxv));
            se += e;
            sle = fmaf(e, lj, sle);
        }
        se += __shfl_xor(se, 1);  sle += __shfl_xor(sle, 1);
        se += __shfl_xor(se, 2);  sle += __shfl_xor(sle, 2);
        se += __shfl_xor(se, 4);  sle += __shfl_xor(sle, 4);
        if (ssub == 0) ss[spix] = sle / se;
    }
    __syncthreads();   // ss ready

    // out = cache + (A*s + B), float4 stores
    {
        const float4 s4 = make_float4(ss[p4 * 4 + 0], ss[p4 * 4 + 1],
                                      ss[p4 * 4 + 2], ss[p4 * 4 + 3]);
        float4* out4 = (float4*)(out + (size_t)b * C_ * HW_ + i0);
        #pragma unroll
        for (int k = 0; k < 8; ++k) {
            const int c = k * 32 + cl;
            const float A = Asc[c], Bc = Bsc[c];
            float4 v = cache[k], o;
            o.x = v.x + fmaf(A, s4.x, Bc);
            o.y = v.y + fmaf(A, s4.y, Bc);
            o.z = v.z + fmaf(A, s4.z, Bc);
            o.w = v.w + fmaf(A, s4.w, Bc);
            out4[(size_t)c * (HW_ / 4) + p4] = o;
        }
    }
}

extern "C" void kernel_launch(void* const* d_in, const int* in_sizes, int n_in,
                              void* d_out, int out_size, void* d_ws, size_t ws_size,
                              hipStream_t stream) {
    const float* img   = (const float*)d_in[0];
    const float* text  = (const float*)d_in[1];
    const float* l     = (const float*)d_in[2];
    const float* Wg1   = (const float*)d_in[3];
    const float* bg1   = (const float*)d_in[4];
    const float* ln_g  = (const float*)d_in[5];
    const float* ln_b  = (const float*)d_in[6];
    const float* Wg2   = (const float*)d_in[7];
    const float* bg2   = (const float*)d_in[8];
    const float* Wq    = (const float*)d_in[9];
    const float* bq    = (const float*)d_in[10];
    const float* Wk    = (const float*)d_in[11];
    // bk (d_in[12]) cancels in the softmax — unused
    const float* Wv    = (const float*)d_in[13];
    const float* bv    = (const float*)d_in[14];
    const float* gamma = (const float*)d_in[15];
    float* out = (float*)d_out;
    float* ws  = (float*)d_ws;

    k_prep<<<64, 512, 0, stream>>>(text, Wg1, bg1, ln_g, ln_b, Wg2, bg2,
                                   Wq, bq, Wk, Wv, ws);
    k_fused<<<576, 256, 0, stream>>>(img, l, bv, gamma, ws, out);
}